// Round 1
// 2297.897 us; speedup vs baseline: 1.3846x; 1.3846x over previous
//
#include <hip/hip_runtime.h>

#define T_LEN 512
#define NB    32
#define HID4  1024
#define DSTR  ((size_t)T_LEN * NB * HID4)   // per-direction xg stride (elements)

typedef short  bf16x8 __attribute__((ext_vector_type(8)));
typedef float  f32x4  __attribute__((ext_vector_type(4)));

static __device__ __forceinline__ unsigned short f2bf(float f) {
  union { float f; unsigned int i; } v; v.f = f;
  unsigned int r = v.i + 0x7FFFu + ((v.i >> 16) & 1u);
  return (unsigned short)(r >> 16);
}
static __device__ __forceinline__ unsigned short f2h(float f) {
  union { _Float16 h; unsigned short u; } v; v.h = (_Float16)f; return v.u;
}
static __device__ __forceinline__ float h2f(unsigned short u) {
  union { unsigned short u; _Float16 h; } v; v.u = u; return (float)v.h;
}
static __device__ __forceinline__ float sigm(float x) {
  return __builtin_amdgcn_rcpf(1.0f + __builtin_amdgcn_exp2f(-1.44269504f * x));
}
static __device__ __forceinline__ float tanh_fast(float x) {
  float e = __builtin_amdgcn_exp2f(2.885390082f * x);
  return 1.0f - 2.0f * __builtin_amdgcn_rcpf(e + 1.0f);
}
// convert 8 consecutive f32 -> bf16x8
static __device__ __forceinline__ bf16x8 cvt8(const float* p) {
  bf16x8 r;
  #pragma unroll
  for (int i = 0; i < 8; ++i) r[i] = (short)f2bf(p[i]);
  return r;
}

// ---------------------------------------------------------------------------
// GEMM: xg = A @ W^T + bias, written in the rec-thread-swizzled layout:
//   xg[dir][t][bg(8)][tid(512)][c(8)]  (f16), c = nh*4 + gt
// Each recurrence thread reads its 8 gate-values as ONE 16B load.
// A: f32 [16384][K], W: f32 [1024][K]. 64x64 tile, 4 waves, K-chunks of 32.
// ---------------------------------------------------------------------------
__global__ __launch_bounds__(256) void gemm_xg(
    const float* __restrict__ A,
    const float* __restrict__ Wf,
    const float* __restrict__ Wb,
    const float* __restrict__ biasf,
    const float* __restrict__ biasb,
    unsigned short* __restrict__ out, int K)
{
  __shared__ __align__(16) unsigned short As[64][40];
  __shared__ __align__(16) unsigned short Bs[64][40];

  const int dir = blockIdx.z;
  const float* W    = dir ? Wb    : Wf;
  const float* bias = dir ? biasb : biasf;
  unsigned short* outd = out + (size_t)dir * DSTR;

  const int m0 = blockIdx.x * 64;
  const int n0 = blockIdx.y * 64;
  const int tid = threadIdx.x;
  const int wv = tid >> 6, lane = tid & 63;
  const int lm = lane & 15, lq = lane >> 4;
  const int mt0 = (wv >> 1) * 32, nt0 = (wv & 1) * 32;
  const int lr = tid >> 2, ls = tid & 3;

  f32x4 acc[2][2];
  #pragma unroll
  for (int a = 0; a < 2; ++a)
    #pragma unroll
    for (int b = 0; b < 2; ++b) acc[a][b] = (f32x4){0.f, 0.f, 0.f, 0.f};

  for (int kc = 0; kc < K; kc += 32) {
    *(bf16x8*)&As[lr][ls * 8] = cvt8(A + (size_t)(m0 + lr) * K + kc + ls * 8);
    *(bf16x8*)&Bs[lr][ls * 8] = cvt8(W + (size_t)(n0 + lr) * K + kc + ls * 8);
    __syncthreads();
    bf16x8 af[2], bfr[2];
    af[0]  = *(const bf16x8*)&As[mt0 + lm][lq * 8];
    af[1]  = *(const bf16x8*)&As[mt0 + 16 + lm][lq * 8];
    bfr[0] = *(const bf16x8*)&Bs[nt0 + lm][lq * 8];
    bfr[1] = *(const bf16x8*)&Bs[nt0 + 16 + lm][lq * 8];
    #pragma unroll
    for (int mt = 0; mt < 2; ++mt)
      #pragma unroll
      for (int nt = 0; nt < 2; ++nt)
        acc[mt][nt] = __builtin_amdgcn_mfma_f32_16x16x32_bf16(af[mt], bfr[nt], acc[mt][nt], 0, 0, 0);
    __syncthreads();
  }

  #pragma unroll
  for (int nt = 0; nt < 2; ++nt) {
    const int n = n0 + nt0 + nt * 16 + lm;       // gate index 0..1023
    const float bv = bias[n];
    const int gt = n >> 8, j = n & 255;
    const int wvr = j >> 5, nh = (j >> 4) & 1, lmr = j & 15;
    const int c = nh * 4 + gt;
    #pragma unroll
    for (int mt = 0; mt < 2; ++mt)
      #pragma unroll
      for (int r4 = 0; r4 < 4; ++r4) {
        const int m = m0 + mt0 + mt * 16 + lq * 4 + r4;   // token = b*T + t
        const int b = m >> 9, t = m & 511;
        const int bg = b >> 2, lqr = b & 3;               // batch-group, local batch
        const int tidr = wvr * 64 + lqr * 16 + lmr;       // recurrence thread id
        outd[((((size_t)t * 8 + bg) * 512 + tidr) << 3) + c] = f2h(acc[mt][nt][r4] + bv);
      }
  }
}

// ---------------------------------------------------------------------------
// Recurrence. Grid = 16 blocks (dir*8 + batch-group of 4), 512 threads (8 waves).
// Each wave owns hidden slice [wave*32, wave*32+32): its i,f,g,o gate rows.
// Batch b (local 0..3) lives at M-tile row 4*b -> acc row r=0 of quad lq is
// batch lq: every lane does gate math for exactly 2 h-values (nh=0,1).
// Rows !=0 mod 4 stay zero (zero-init h buffers) -> MFMA padding is harmless
// (rows are independent). 4x less gate VALU + stores per thread vs 16-batch
// blocks; MFMA count per block unchanged (padded), but 4x more CUs.
// afrag is hoisted across nh (kt-outer loop): halves A-frag LDS reads.
// STATIC LDS (144 KB): 1 block/CU. waves_per_eu(2,2) -> 256-VGPR budget so
// the 192 weight regs (kt 0..5) stay resident; kt 6,7 in LDS.
// ---------------------------------------------------------------------------
__global__ __launch_bounds__(512) __attribute__((amdgpu_waves_per_eu(2, 2)))
void lstm_rec(
    const unsigned short* __restrict__ xg,   // [2][T][8][512][8] f16 (swizzled)
    const float* __restrict__ whh_f,         // [1024][256] f32
    const float* __restrict__ whh_b,
    float* __restrict__ out)                 // [32][T][512] f32, col off dir*256
{
  __shared__ __align__(16) unsigned short ldsB[65536];  // 128 frags * 1 KB
  __shared__ __align__(16) unsigned short hbuf[8192];   // [2][8][4][16][8]

  const int dir = blockIdx.x >> 3, bg = blockIdx.x & 7;
  const int b0 = bg * 4;
  const float* whh = dir ? whh_b : whh_f;
  const unsigned short* xgd = xg + (size_t)dir * DSTR;
  const int wave = threadIdx.x >> 6, lane = threadIdx.x & 63;
  const int lm = lane & 15, lq = lane >> 4;
  const int j0 = wave * 32;

  // ---- preload W_hh fragments (B-operand: n = lane&15, k = lq*8 + j) ----
  bf16x8 breg[4][2][6];
  #pragma unroll
  for (int gt = 0; gt < 4; ++gt)
    #pragma unroll
    for (int nh = 0; nh < 2; ++nh) {
      const float* wrow = whh + (size_t)(gt * 256 + j0 + nh * 16 + lm) * 256;
      #pragma unroll
      for (int kt = 0; kt < 6; ++kt)
        breg[gt][nh][kt] = cvt8(wrow + kt * 32 + lq * 8);
      #pragma unroll
      for (int kt = 6; kt < 8; ++kt) {
        const int tl = wave * 16 + gt * 4 + nh * 2 + (kt - 6);
        *(bf16x8*)(ldsB + ((size_t)tl * 64 + lane) * 8) = cvt8(wrow + kt * 32 + lq * 8);
      }
    }

  for (int i = threadIdx.x; i < 8192; i += 512) hbuf[i] = 0;
  float creg[2] = {0.f, 0.f};

  // output base: this thread's batch row is b0+lq, hidden col j0+lm (+nh*16)
  float* obase = out + (size_t)(b0 + lq) * T_LEN * 512 + dir * 256 + j0 + lm;

  // h write slot (A-frag-native): value (m=4*lq, col jfull=j0+nh*16+lm) ->
  // kt'=wave, quad'=nh*2+(lm>>3), row'=4*lq, e=lm&7; nh adds 256 shorts.
  const int wb0 = wave * 512 + (lm >> 3) * 128 + lq * 32 + (lm & 7);

  __syncthreads();

  for (int s = 0; s < T_LEN; ++s) {
    const int tt = dir ? (T_LEN - 1 - s) : s;
    const unsigned short* hr = hbuf + (s & 1) * 4096;
    unsigned short* hw = hbuf + ((s + 1) & 1) * 4096;

    // this thread's 8 xg gate-values for step tt: one 16B load
    const bf16x8 xq = *(const bf16x8*)(xgd + ((((size_t)tt * 8 + bg) * 512 + threadIdx.x) << 3));

    f32x4 acc[2][4];
    #pragma unroll
    for (int nh = 0; nh < 2; ++nh)
      #pragma unroll
      for (int gt = 0; gt < 4; ++gt) acc[nh][gt] = (f32x4){0.f, 0.f, 0.f, 0.f};

    #pragma unroll
    for (int kt = 0; kt < 8; ++kt) {
      const bf16x8 afrag = *(const bf16x8*)(hr + kt * 512 + lane * 8);
      #pragma unroll
      for (int nh = 0; nh < 2; ++nh)
        #pragma unroll
        for (int gt = 0; gt < 4; ++gt) {
          bf16x8 bfr;
          if (kt < 6) bfr = breg[gt][nh][kt];
          else        bfr = *(const bf16x8*)(ldsB + ((size_t)(wave * 16 + gt * 4 + nh * 2 + (kt - 6)) * 64 + lane) * 8);
          acc[nh][gt] = __builtin_amdgcn_mfma_f32_16x16x32_bf16(afrag, bfr, acc[nh][gt], 0, 0, 0);
        }
    }

    const size_t tto = (size_t)tt * 512;
    #pragma unroll
    for (int nh = 0; nh < 2; ++nh) {
      const float iv = sigm(acc[nh][0][0] + h2f((unsigned short)xq[nh * 4 + 0]));
      const float fv = sigm(acc[nh][1][0] + h2f((unsigned short)xq[nh * 4 + 1]));
      const float gv = tanh_fast(acc[nh][2][0] + h2f((unsigned short)xq[nh * 4 + 2]));
      const float ov = sigm(acc[nh][3][0] + h2f((unsigned short)xq[nh * 4 + 3]));
      const float cv = fv * creg[nh] + iv * gv;
      creg[nh] = cv;
      const float hv = ov * tanh_fast(cv);
      hw[wb0 + nh * 256] = f2bf(hv);
      obase[tto + nh * 16] = hv;
    }
    __syncthreads();
  }
}

// ---------------------------------------------------------------------------
extern "C" void kernel_launch(void* const* d_in, const int* in_sizes, int n_in,
                              void* d_out, int out_size, void* d_ws, size_t ws_size,
                              hipStream_t stream) {
  const float* x     = (const float*)d_in[0];
  const float* wih0f = (const float*)d_in[1];
  const float* whh0f = (const float*)d_in[2];
  const float* b0f   = (const float*)d_in[3];
  const float* wih0b = (const float*)d_in[4];
  const float* whh0b = (const float*)d_in[5];
  const float* b0b   = (const float*)d_in[6];
  const float* wih1f = (const float*)d_in[7];
  const float* whh1f = (const float*)d_in[8];
  const float* b1f   = (const float*)d_in[9];
  const float* wih1b = (const float*)d_in[10];
  const float* whh1b = (const float*)d_in[11];
  const float* b1b   = (const float*)d_in[12];
  float* out = (float*)d_out;

  // ws: xg only — [2][T][8][512][8] f16 = 64 MiB. Layer-0 hidden states are
  // routed through d_out (f32, fully overwritten by the layer-1 recurrence).
  unsigned short* xg = (unsigned short*)d_ws;

  gemm_xg<<<dim3(256, 16, 2), 256, 0, stream>>>(x,   wih0f, wih0b, b0f, b0b, xg, 256);
  lstm_rec<<<16, 512, 0, stream>>>(xg, whh0f, whh0b, out);   // h1 -> d_out (f32)
  gemm_xg<<<dim3(256, 16, 2), 256, 0, stream>>>(out, wih1f, wih1b, b1f, b1b, xg, 512);
  lstm_rec<<<16, 512, 0, stream>>>(xg, whh1f, whh1b, out);
}

// Round 2
// 2058.147 us; speedup vs baseline: 1.5459x; 1.1165x over previous
//
#include <hip/hip_runtime.h>

#define T_LEN 512
#define NB    32
#define HID4  1024
#define DSTR  ((size_t)T_LEN * NB * HID4)   // per-direction xg stride (elements)

typedef short  bf16x8 __attribute__((ext_vector_type(8)));
typedef float  f32x4  __attribute__((ext_vector_type(4)));

static __device__ __forceinline__ unsigned short f2bf(float f) {
  union { float f; unsigned int i; } v; v.f = f;
  unsigned int r = v.i + 0x7FFFu + ((v.i >> 16) & 1u);
  return (unsigned short)(r >> 16);
}
static __device__ __forceinline__ unsigned short f2h(float f) {
  union { _Float16 h; unsigned short u; } v; v.h = (_Float16)f; return v.u;
}
static __device__ __forceinline__ float h2f(unsigned short u) {
  union { unsigned short u; _Float16 h; } v; v.u = u; return (float)v.h;
}
static __device__ __forceinline__ float sigm(float x) {
  return __builtin_amdgcn_rcpf(1.0f + __builtin_amdgcn_exp2f(-1.44269504f * x));
}
static __device__ __forceinline__ float tanh_fast(float x) {
  float e = __builtin_amdgcn_exp2f(2.885390082f * x);
  return 1.0f - 2.0f * __builtin_amdgcn_rcpf(e + 1.0f);
}
// convert 8 consecutive f32 -> bf16x8
static __device__ __forceinline__ bf16x8 cvt8(const float* p) {
  bf16x8 r;
  #pragma unroll
  for (int i = 0; i < 8; ++i) r[i] = (short)f2bf(p[i]);
  return r;
}

// ---------------------------------------------------------------------------
// GEMM: xg = A @ W^T + bias, written in the rec-thread-swizzled layout:
//   xg[dir][t][bg(8)][tid(512)][c(8)]  (f16), c = nh*4 + gt
// Each recurrence thread reads its 8 gate-values as ONE 16B load.
// A: f32 [16384][K], W: f32 [1024][K]. 64x64 tile, 4 waves, K-chunks of 32.
// ---------------------------------------------------------------------------
__global__ __launch_bounds__(256) void gemm_xg(
    const float* __restrict__ A,
    const float* __restrict__ Wf,
    const float* __restrict__ Wb,
    const float* __restrict__ biasf,
    const float* __restrict__ biasb,
    unsigned short* __restrict__ out, int K)
{
  __shared__ __align__(16) unsigned short As[64][40];
  __shared__ __align__(16) unsigned short Bs[64][40];

  const int dir = blockIdx.z;
  const float* W    = dir ? Wb    : Wf;
  const float* bias = dir ? biasb : biasf;
  unsigned short* outd = out + (size_t)dir * DSTR;

  const int m0 = blockIdx.x * 64;
  const int n0 = blockIdx.y * 64;
  const int tid = threadIdx.x;
  const int wv = tid >> 6, lane = tid & 63;
  const int lm = lane & 15, lq = lane >> 4;
  const int mt0 = (wv >> 1) * 32, nt0 = (wv & 1) * 32;
  const int lr = tid >> 2, ls = tid & 3;

  f32x4 acc[2][2];
  #pragma unroll
  for (int a = 0; a < 2; ++a)
    #pragma unroll
    for (int b = 0; b < 2; ++b) acc[a][b] = (f32x4){0.f, 0.f, 0.f, 0.f};

  for (int kc = 0; kc < K; kc += 32) {
    *(bf16x8*)&As[lr][ls * 8] = cvt8(A + (size_t)(m0 + lr) * K + kc + ls * 8);
    *(bf16x8*)&Bs[lr][ls * 8] = cvt8(W + (size_t)(n0 + lr) * K + kc + ls * 8);
    __syncthreads();
    bf16x8 af[2], bfr[2];
    af[0]  = *(const bf16x8*)&As[mt0 + lm][lq * 8];
    af[1]  = *(const bf16x8*)&As[mt0 + 16 + lm][lq * 8];
    bfr[0] = *(const bf16x8*)&Bs[nt0 + lm][lq * 8];
    bfr[1] = *(const bf16x8*)&Bs[nt0 + 16 + lm][lq * 8];
    #pragma unroll
    for (int mt = 0; mt < 2; ++mt)
      #pragma unroll
      for (int nt = 0; nt < 2; ++nt)
        acc[mt][nt] = __builtin_amdgcn_mfma_f32_16x16x32_bf16(af[mt], bfr[nt], acc[mt][nt], 0, 0, 0);
    __syncthreads();
  }

  #pragma unroll
  for (int nt = 0; nt < 2; ++nt) {
    const int n = n0 + nt0 + nt * 16 + lm;       // gate index 0..1023
    const float bv = bias[n];
    const int gt = n >> 8, j = n & 255;
    const int wvr = j >> 5, nh = (j >> 4) & 1, lmr = j & 15;
    const int c = nh * 4 + gt;
    #pragma unroll
    for (int mt = 0; mt < 2; ++mt)
      #pragma unroll
      for (int r4 = 0; r4 < 4; ++r4) {
        const int m = m0 + mt0 + mt * 16 + lq * 4 + r4;   // token = b*T + t
        const int b = m >> 9, t = m & 511;
        const int bg = b >> 2, lqr = b & 3;               // batch-group, local batch
        const int tidr = wvr * 64 + lqr * 16 + lmr;       // recurrence thread id
        outd[((((size_t)t * 8 + bg) * 512 + tidr) << 3) + c] = f2h(acc[mt][nt][r4] + bv);
      }
  }
}

// ---------------------------------------------------------------------------
// Recurrence. Grid = 16 blocks (dir*8 + batch-group of 4), 512 threads (8 waves).
// Each wave owns hidden slice [wave*32, wave*32+32): its i,f,g,o gate rows.
// Batch b (local 0..3) lives at M-tile row 4*b -> acc row r=0 of quad lq is
// batch lq: every lane does gate math for exactly 2 h-values (nh=0,1).
// Rows !=0 mod 4 stay zero (zero-init h buffers) -> MFMA padding is harmless.
// afrag is hoisted across nh (kt-outer loop): halves A-frag LDS reads.
// STATIC LDS (144 KB): 1 block/CU. waves_per_eu(2,2) -> 256-reg budget so
// the 48 weight frags (kt 0..5) stay resident (VGPR+AGPR); kt 6,7 in LDS.
//
// Barrier discipline: raw s_barrier + explicit lgkmcnt(0) ONLY. __syncthreads
// would emit s_waitcnt vmcnt(0) before s_barrier, draining the 2 global
// stores + xq load EVERY step (~2000 cy/step of pure drain). h is
// double-buffered and every wave consumes its hr reads (MFMA) before the
// barrier, so LDS-ordering alone is sufficient. xq is software-pipelined one
// step ahead so its L2/L3 latency spans a full step across the raw barrier.
// ---------------------------------------------------------------------------
__global__ __launch_bounds__(512) __attribute__((amdgpu_waves_per_eu(2, 2)))
void lstm_rec(
    const unsigned short* __restrict__ xg,   // [2][T][8][512][8] f16 (swizzled)
    const float* __restrict__ whh_f,         // [1024][256] f32
    const float* __restrict__ whh_b,
    float* __restrict__ out)                 // [32][T][512] f32, col off dir*256
{
  __shared__ __align__(16) unsigned short ldsB[65536];  // 128 frags * 1 KB
  __shared__ __align__(16) unsigned short hbuf[8192];   // [2][8][4][16][8]

  const int dir = blockIdx.x >> 3, bg = blockIdx.x & 7;
  const int b0 = bg * 4;
  const float* whh = dir ? whh_b : whh_f;
  const unsigned short* xgd = xg + (size_t)dir * DSTR;
  const int wave = threadIdx.x >> 6, lane = threadIdx.x & 63;
  const int lm = lane & 15, lq = lane >> 4;
  const int j0 = wave * 32;

  // ---- preload W_hh fragments (B-operand: n = lane&15, k = lq*8 + j) ----
  bf16x8 breg[4][2][6];
  #pragma unroll
  for (int gt = 0; gt < 4; ++gt)
    #pragma unroll
    for (int nh = 0; nh < 2; ++nh) {
      const float* wrow = whh + (size_t)(gt * 256 + j0 + nh * 16 + lm) * 256;
      #pragma unroll
      for (int kt = 0; kt < 6; ++kt)
        breg[gt][nh][kt] = cvt8(wrow + kt * 32 + lq * 8);
      #pragma unroll
      for (int kt = 6; kt < 8; ++kt) {
        const int tl = wave * 16 + gt * 4 + nh * 2 + (kt - 6);
        *(bf16x8*)(ldsB + ((size_t)tl * 64 + lane) * 8) = cvt8(wrow + kt * 32 + lq * 8);
      }
    }

  for (int i = threadIdx.x; i < 8192; i += 512) hbuf[i] = 0;
  float creg[2] = {0.f, 0.f};

  // output base: this thread's batch row is b0+lq, hidden col j0+lm (+nh*16)
  float* obase = out + (size_t)(b0 + lq) * T_LEN * 512 + dir * 256 + j0 + lm;

  // h write slot (A-frag-native): value (m=4*lq, col jfull=j0+nh*16+lm) ->
  // kt'=wave, quad'=nh*2+(lm>>3), row'=4*lq, e=lm&7; nh adds 256 shorts.
  const int wb0 = wave * 512 + (lm >> 3) * 128 + lq * 32 + (lm & 7);

  // prefetch xq for step 0 (one 16B load per thread per step)
  const int tt0 = dir ? (T_LEN - 1) : 0;
  bf16x8 xq_n = *(const bf16x8*)(xgd + ((((size_t)tt0 * 8 + bg) * 512 + threadIdx.x) << 3));

  __syncthreads();

  for (int s = 0; s < T_LEN; ++s) {
    const int tt = dir ? (T_LEN - 1 - s) : s;
    const unsigned short* hr = hbuf + (s & 1) * 4096;
    unsigned short* hw = hbuf + ((s + 1) & 1) * 4096;

    const bf16x8 xq = xq_n;   // consumed this step (vmcnt wait covers prefetch)

    // issue prefetch for step s+1 right away: latency spans the whole step
    const int s1 = (s + 1 < T_LEN) ? (s + 1) : s;
    const int tt1 = dir ? (T_LEN - 1 - s1) : s1;
    xq_n = *(const bf16x8*)(xgd + ((((size_t)tt1 * 8 + bg) * 512 + threadIdx.x) << 3));

    f32x4 acc[2][4];
    #pragma unroll
    for (int nh = 0; nh < 2; ++nh)
      #pragma unroll
      for (int gt = 0; gt < 4; ++gt) acc[nh][gt] = (f32x4){0.f, 0.f, 0.f, 0.f};

    #pragma unroll
    for (int kt = 0; kt < 8; ++kt) {
      const bf16x8 afrag = *(const bf16x8*)(hr + kt * 512 + lane * 8);
      #pragma unroll
      for (int nh = 0; nh < 2; ++nh)
        #pragma unroll
        for (int gt = 0; gt < 4; ++gt) {
          bf16x8 bfr;
          if (kt < 6) bfr = breg[gt][nh][kt];
          else        bfr = *(const bf16x8*)(ldsB + ((size_t)(wave * 16 + gt * 4 + nh * 2 + (kt - 6)) * 64 + lane) * 8);
          acc[nh][gt] = __builtin_amdgcn_mfma_f32_16x16x32_bf16(afrag, bfr, acc[nh][gt], 0, 0, 0);
        }
    }

    const size_t tto = (size_t)tt * 512;
    #pragma unroll
    for (int nh = 0; nh < 2; ++nh) {
      const float iv = sigm(acc[nh][0][0] + h2f((unsigned short)xq[nh * 4 + 0]));
      const float fv = sigm(acc[nh][1][0] + h2f((unsigned short)xq[nh * 4 + 1]));
      const float gv = tanh_fast(acc[nh][2][0] + h2f((unsigned short)xq[nh * 4 + 2]));
      const float ov = sigm(acc[nh][3][0] + h2f((unsigned short)xq[nh * 4 + 3]));
      const float cv = fv * creg[nh] + iv * gv;
      creg[nh] = cv;
      const float hv = ov * tanh_fast(cv);
      hw[wb0 + nh * 256] = f2bf(hv);
      obase[tto + nh * 16] = hv;
    }

    // LDS-only fence + raw barrier: global stores/load stay in flight.
    asm volatile("s_waitcnt lgkmcnt(0)" ::: "memory");
    __builtin_amdgcn_s_barrier();
  }
}

// ---------------------------------------------------------------------------
extern "C" void kernel_launch(void* const* d_in, const int* in_sizes, int n_in,
                              void* d_out, int out_size, void* d_ws, size_t ws_size,
                              hipStream_t stream) {
  const float* x     = (const float*)d_in[0];
  const float* wih0f = (const float*)d_in[1];
  const float* whh0f = (const float*)d_in[2];
  const float* b0f   = (const float*)d_in[3];
  const float* wih0b = (const float*)d_in[4];
  const float* whh0b = (const float*)d_in[5];
  const float* b0b   = (const float*)d_in[6];
  const float* wih1f = (const float*)d_in[7];
  const float* whh1f = (const float*)d_in[8];
  const float* b1f   = (const float*)d_in[9];
  const float* wih1b = (const float*)d_in[10];
  const float* whh1b = (const float*)d_in[11];
  const float* b1b   = (const float*)d_in[12];
  float* out = (float*)d_out;

  // ws: xg only — [2][T][8][512][8] f16 = 64 MiB. Layer-0 hidden states are
  // routed through d_out (f32, fully overwritten by the layer-1 recurrence).
  unsigned short* xg = (unsigned short*)d_ws;

  gemm_xg<<<dim3(256, 16, 2), 256, 0, stream>>>(x,   wih0f, wih0b, b0f, b0b, xg, 256);
  lstm_rec<<<16, 512, 0, stream>>>(xg, whh0f, whh0b, out);   // h1 -> d_out (f32)
  gemm_xg<<<dim3(256, 16, 2), 256, 0, stream>>>(out, wih1f, wih1b, b1f, b1b, xg, 512);
  lstm_rec<<<16, 512, 0, stream>>>(xg, whh1f, whh1b, out);
}